// Round 17
// baseline (339.351 us; speedup 1.0000x reference)
//
#include <hip/hip_runtime.h>

#define D_ 64
#define H_ 128
#define W_ 128
#define VOL (D_*H_*W_)   // 1048576 = 1<<20
#define NF 4             // {pred,target} x {b0,b1}
#define LARGEF 1e8f
#define SW(r,c) (((r) << 7) + ((c) ^ ((r) & 31)))   // bank-conflict-free both axes
#define GRID 256
#define TPB 1024

struct Ctl {                 // lives at ws[0]; zeroed by the captured memset node
  double acc[2];
  unsigned ticket;
  unsigned bar[3];
};

__device__ __forceinline__ bool maskv(float v, int which) {
  return which ? (v != 0.0f) : (v > 0.0f);   // sigmoid(v)>0.5 <=> v>0
}

// Device-scope grid barrier. Safe: grid=256 blocks; capacity is >=2 blocks/CU
// (64KB/160KB LDS, 1024/2048 threads) so all 256 blocks are co-resident
// regardless of packing -> no deadlock.
__device__ __forceinline__ void gbar(unsigned* ctr) {
  __syncthreads();
  if (threadIdx.x == 0) {
    __threadfence();                               // release our writes
    atomicAdd(ctr, 1u);
    while (atomicAdd(ctr, 0u) < GRID) __builtin_amdgcn_s_sleep(2);
  }
  __syncthreads();
  __threadfence();                                 // acquire remote writes
}

__global__ __launch_bounds__(TPB) void k_fused(const float* __restrict__ pred,
                                               const float* __restrict__ targ,
                                               unsigned char* __restrict__ surf,
                                               unsigned char* __restrict__ zdist,
                                               unsigned short* __restrict__ d2s,
                                               Ctl* __restrict__ ctl,
                                               float* __restrict__ out) {
  __shared__ __align__(16) unsigned char smem[65536];   // tile / fwd / wsum union

  // ================= phase 1: surface extraction (4 uchar4 units/thread) ====
  #pragma unroll
  for (int it = 0; it < 4; ++it) {
    int idx = blockIdx.x * TPB + threadIdx.x + it * (GRID * TPB); // [0, NF*VOL/4)
    int f = idx >> 18;                               // VOL/4 = 2^18
    int q = idx & 262143;
    int which = f & 1;
    const float* __restrict__ src = (which ? targ : pred) + ((size_t)(f >> 1) << 20);
    const float4* __restrict__ s4 = (const float4*)src;
    int v = q << 2;
    int z = v >> 14, y = (v >> 7) & 127, x = v & 127;
    float4 c = s4[q];
    bool m0 = maskv(c.x, which), m1 = maskv(c.y, which);
    bool m2 = maskv(c.z, which), m3 = maskv(c.w, which);
    bool ym0=false, ym1=false, ym2=false, ym3=false;
    bool yp0=false, yp1=false, yp2=false, yp3=false;
    bool zm0=false, zm1=false, zm2=false, zm3=false;
    bool zp0=false, zp1=false, zp2=false, zp3=false;
    if (y > 0)   { float4 t = s4[q - 32];   ym0=maskv(t.x,which); ym1=maskv(t.y,which); ym2=maskv(t.z,which); ym3=maskv(t.w,which); }
    if (y < 127) { float4 t = s4[q + 32];   yp0=maskv(t.x,which); yp1=maskv(t.y,which); yp2=maskv(t.z,which); yp3=maskv(t.w,which); }
    if (z > 0)   { float4 t = s4[q - 4096]; zm0=maskv(t.x,which); zm1=maskv(t.y,which); zm2=maskv(t.z,which); zm3=maskv(t.w,which); }
    if (z < 63)  { float4 t = s4[q + 4096]; zp0=maskv(t.x,which); zp1=maskv(t.y,which); zp2=maskv(t.z,which); zp3=maskv(t.w,which); }
    bool lm = (x > 0)   ? maskv(src[v - 1], which) : false;
    bool rm = (x < 124) ? maskv(src[v + 4], which) : false;
    bool e0 = m0 && lm && m1 && ym0 && yp0 && zm0 && zp0;
    bool e1 = m1 && m0 && m2 && ym1 && yp1 && zm1 && zp1;
    bool e2 = m2 && m1 && m3 && ym2 && yp2 && zm2 && zp2;
    bool e3 = m3 && m2 && rm && ym3 && yp3 && zm3 && zp3;
    uchar4 o;
    o.x = (unsigned char)(m0 && !e0);
    o.y = (unsigned char)(m1 && !e1);
    o.z = (unsigned char)(m2 && !e2);
    o.w = (unsigned char)(m3 && !e3);
    ((uchar4*)surf)[idx] = o;
  }
  gbar(&ctl->bar[0]);

  // ================= phase 2: z two-scan -> u8 zdist (255 = none) ===========
  {
    unsigned short (*fwd)[256] = (unsigned short (*)[256])smem;  // 32 KB
    if (threadIdx.x < 256) {
      int g = blockIdx.x * 256 + threadIdx.x;        // 65536 columns
      int f = g >> 14, yx = g & 16383;
      const unsigned char* s = surf + (f << 20) + yx;
      unsigned char* o = zdist + (f << 20) + yx;
      int d = 255;
      #pragma unroll 16
      for (int z = 0; z < D_; ++z) {
        d = s[z << 14] ? 0 : min(d + 1, 255);
        fwd[z][threadIdx.x] = (unsigned short)d;
      }
      int dd = 255;
      #pragma unroll 8
      for (int z = D_ - 1; z >= 0; --z) {
        int fv = fwd[z][threadIdx.x];
        dd = (fv == 0) ? 0 : min(dd + 1, 255);
        o[z << 14] = (unsigned char)min(fv, dd);
      }
    }
  }
  gbar(&ctl->bar[1]);

  // ================= phase 3: y+x EDT on one (f,z) slab (R15 body) ==========
  {
    float* tile = (float*)smem;                      // 64 KB
    int f = blockIdx.x >> 6, z = blockIdx.x & 63;
    const unsigned char* zsrc = zdist + (f << 20) + (z << 14);
    for (int e = threadIdx.x; e < 16384; e += TPB) { // SCALAR stage (R14 lesson)
      int r = e >> 7, c = e & 127;
      int b = zsrc[e];
      float v = (b == 255) ? LARGEF : (float)(b * b);
      tile[SW(r, c)] = v + (float)(r * r);           // zd^2 + y^2
    }
    __syncthreads();
    const int R = 16;
    int tp = threadIdx.x & 127, tw = threadIdx.x >> 7;
    float best[R], fi[R];
    float fb = (float)(tw * R);
    float tmax = 0.0f;
    #pragma unroll
    for (int u = 0; u < R; ++u) {
      fi[u] = fb + (float)u; best[u] = 3.0e8f;
      float tv = tile[SW(tw * R + u, tp)] - fi[u] * fi[u];
      tmax = fmaxf(tmax, tv);
    }
    #pragma unroll
    for (int o = 1; o < 64; o <<= 1) tmax = fmaxf(tmax, __shfl_xor(tmax, o));
    int rad = (int)sqrtf(tmax);
    int jlo = max(0, tw * R - rad), jhi = min(H_ - 1, tw * R + (R - 1) + rad);
    for (int j = jlo; j <= jhi; ++j) {
      float t = tile[SW(j, tp)];
      float m2j = -2.0f * (float)j;
      #pragma unroll
      for (int u = 0; u < R; ++u)
        best[u] = fminf(best[u], __builtin_fmaf(m2j, fi[u], t));
    }
    __syncthreads();
    float fx2 = (float)(tp * tp);
    #pragma unroll
    for (int u = 0; u < R; ++u)
      tile[SW(tw * R + u, tp)] = best[u] + fi[u] * fi[u] + fx2;
    __syncthreads();
    tmax = 0.0f;
    #pragma unroll
    for (int u = 0; u < R; ++u) {
      best[u] = 3.0e8f;
      float tv = tile[SW(tp, tw * R + u)] - fi[u] * fi[u];
      tmax = fmaxf(tmax, tv);
    }
    #pragma unroll
    for (int o = 1; o < 64; o <<= 1) tmax = fmaxf(tmax, __shfl_xor(tmax, o));
    rad = (int)sqrtf(tmax);
    jlo = max(0, tw * R - rad); jhi = min(W_ - 1, tw * R + (R - 1) + rad);
    for (int j = jlo; j <= jhi; ++j) {
      float t = tile[SW(tp, j)];                     // yEDT + j^2 (fold IS the term)
      float m2j = -2.0f * (float)j;
      #pragma unroll
      for (int u = 0; u < R; ++u)
        best[u] = fminf(best[u], __builtin_fmaf(m2j, fi[u], t));
    }
    unsigned pk[8];
    #pragma unroll
    for (int p = 0; p < 8; ++p) {
      float dlo = best[2*p]     + fi[2*p]     * fi[2*p];
      float dhi = best[2*p + 1] + fi[2*p + 1] * fi[2*p + 1];
      unsigned lo = (dlo > 65504.f) ? 65535u : (unsigned)dlo;
      unsigned hi = (dhi > 65504.f) ? 65535u : (unsigned)dhi;
      pk[p] = lo | (hi << 16);
    }
    uint4* ob = (uint4*)(d2s + (f << 20) + (z << 14) + (tp << 7) + tw * R);
    ob[0] = make_uint4(pk[0], pk[1], pk[2], pk[3]);
    ob[1] = make_uint4(pk[4], pk[5], pk[6], pk[7]);
  }
  gbar(&ctl->bar[2]);

  // ================= phase 4: smooth-L1 pair reduce + finalize ==============
  {
    int v = blockIdx.x * TPB + threadIdx.x;          // [0, 262144): 1 uint4-pair
    int b = v >> 17;                                 // block fully within one b
    int idx = v & 131071;                            // VOL/8 per field
    const uint4* dp = (const uint4*)(d2s + ((size_t)(b * 2 + 0) << 20));
    const uint4* dt = (const uint4*)(d2s + ((size_t)(b * 2 + 1) << 20));
    uint4 A = dp[idx], C = dt[idx];
    unsigned aw[4] = {A.x, A.y, A.z, A.w};
    unsigned cw[4] = {C.x, C.y, C.z, C.w};
    double s = 0.0;
    #pragma unroll
    for (int k = 0; k < 4; ++k) {
      unsigned a0 = aw[k] & 0xFFFFu, a1 = aw[k] >> 16;
      unsigned c0 = cw[k] & 0xFFFFu, c1 = cw[k] >> 16;
      float da0 = sqrtf(a0 == 65535u ? LARGEF : (float)a0);
      float da1 = sqrtf(a1 == 65535u ? LARGEF : (float)a1);
      float dc0 = sqrtf(c0 == 65535u ? LARGEF : (float)c0);
      float dc1 = sqrtf(c1 == 65535u ? LARGEF : (float)c1);
      float d0 = da0 - dc0, d1 = da1 - dc1;
      float b0 = fabsf(d0), b1 = fabsf(d1);
      s += (double)(b0 < 1.0f ? 0.5f * d0 * d0 : b0 - 0.5f);
      s += (double)(b1 < 1.0f ? 0.5f * d1 * d1 : b1 - 0.5f);
    }
    #pragma unroll
    for (int o = 32; o > 0; o >>= 1) s += __shfl_down(s, o);
    double* wsum = (double*)smem;                    // tile is dead; reuse
    if ((threadIdx.x & 63) == 0) wsum[threadIdx.x >> 6] = s;
    __syncthreads();
    if (threadIdx.x == 0) {
      double bs = 0.0;
      #pragma unroll
      for (int w = 0; w < TPB / 64; ++w) bs += wsum[w];
      atomicAdd(&ctl->acc[b], bs);
      __threadfence();
      unsigned done = atomicAdd(&ctl->ticket, 1u);
      if (done == GRID - 1) {
        __threadfence();
        out[0] = (float)(0.5 * (ctl->acc[0] / (double)VOL + ctl->acc[1] / (double)VOL));
      }
    }
  }
}

extern "C" void kernel_launch(void* const* d_in, const int* in_sizes, int n_in,
                              void* d_out, int out_size, void* d_ws, size_t ws_size,
                              hipStream_t stream) {
  const float* pred = (const float*)d_in[0];
  const float* targ = (const float*)d_in[1];
  Ctl* ctl = (Ctl*)d_ws;                                              // 32 B
  unsigned char*  surf  = (unsigned char*)d_ws + 1024;                // 4 MB
  unsigned char*  zdist = surf + ((size_t)NF << 20);                  // 4 MB
  unsigned short* d2s   = (unsigned short*)(zdist + ((size_t)NF << 20)); // 8 MB
  float* out = (float*)d_out;

  hipMemsetAsync(ctl, 0, sizeof(Ctl), stream);       // captured as a graph node
  k_fused<<<GRID, TPB, 0, stream>>>(pred, targ, surf, zdist, d2s, ctl, out);
}